// Round 8
// baseline (295.092 us; speedup 1.0000x reference)
//
#include <hip/hip_runtime.h>

// QuantAttnBlock on gfx950, round 8: fuse quant+PV into k_qpv.
// P (quantized attn) lives only in a 4 KB LDS tile in B-fragment-ready
// layout (swizzled u32 writes, aligned uint4 reads, no perms, no HBM).
// aq buffer (67 MB x2 traffic) and k_pv eliminated.

#define Bb 4
#define Cc 256
#define Nn 4096
#define NGRP 32
#define LOG2E 1.4426950408889634f

typedef unsigned short u16;
typedef unsigned int   u32;
typedef unsigned char  u8;
typedef __attribute__((ext_vector_type(8))) short bf16x8;
typedef __attribute__((ext_vector_type(4))) float f32x4;
typedef __attribute__((ext_vector_type(4))) int   i32x4;

#define MFMA16(a,b,c)    __builtin_amdgcn_mfma_f32_16x16x32_bf16((a),(b),(c),0,0,0)
#define MFMA_I8(a,b,c)   __builtin_amdgcn_mfma_i32_16x16x64_i8((a),(b),(c),0,0,0)

static __device__ __forceinline__ u16 f2bf(float x){
  u32 u = __float_as_uint(x);
  u += 0x7fffu + ((u >> 16) & 1u);
  return (u16)(u >> 16);
}
static __device__ __forceinline__ float bf2f(u16 h){ return __uint_as_float(((u32)h) << 16); }

union U64c { u16 u[4]; uint2 v; };

// ---------------- GroupNorm stats ----------------
__global__ __launch_bounds__(256) void k_gn_stats(const float* __restrict__ x,
                                                  float* __restrict__ mu, float* __restrict__ rs){
  int bg = blockIdx.x;
  const float4* p = (const float4*)(x + (size_t)bg * (8 * Nn));
  float s = 0.f, q = 0.f;
  for (int i = threadIdx.x; i < 8*Nn/4; i += 256){
    float4 v = p[i];
    s += v.x + v.y + v.z + v.w;
    q += v.x*v.x + v.y*v.y + v.z*v.z + v.w*v.w;
  }
  __shared__ float rsum[256], rsq[256];
  rsum[threadIdx.x] = s; rsq[threadIdx.x] = q;
  __syncthreads();
  for (int off = 128; off > 0; off >>= 1){
    if (threadIdx.x < off){ rsum[threadIdx.x] += rsum[threadIdx.x+off]; rsq[threadIdx.x] += rsq[threadIdx.x+off]; }
    __syncthreads();
  }
  if (threadIdx.x == 0){
    const float inv = 1.0f / (8*Nn);
    float m = rsum[0]*inv;
    float var = rsq[0]*inv - m*m;
    mu[bg] = m; rs[bg] = rsqrtf(var + 1e-6f);
  }
}

// ------------- weight split: 4 matrices f32 -> hi/lo bf16 -------------
__global__ __launch_bounds__(256) void k_wsplit(const float* __restrict__ wq, const float* __restrict__ wk,
                                                const float* __restrict__ wv, const float* __restrict__ wp,
                                                u16* __restrict__ WH, u16* __restrict__ WL){
  int gid = blockIdx.x*256 + threadIdx.x;
  int mat = gid >> 16, idx = gid & 65535;
  const float* src = (mat == 0) ? wq : (mat == 1) ? wk : (mat == 2) ? wv : wp;
  float w = src[idx];
  u16 h = f2bf(w);
  WH[gid] = h;
  WL[gid] = f2bf(w - bf2f(h));
}

// ------------- GroupNorm apply + transpose -> hT hi/lo [b][n][c] -------------
__global__ __launch_bounds__(256) void k_gn_apply(const float* __restrict__ x,
                                                  const float* __restrict__ gsc, const float* __restrict__ gbi,
                                                  const float* __restrict__ mu, const float* __restrict__ rs,
                                                  u16* __restrict__ hhi, u16* __restrict__ hlo){
  int nt = blockIdx.x, ct = blockIdx.y, b = blockIdx.z;
  int n0 = nt*64, c0 = ct*64;
  __shared__ float yt[64*65];
  __shared__ float sa[64], sb[64];
  int t = threadIdx.x;
  if (t < 64){
    int c = c0 + t;
    int bg = b*NGRP + (c >> 3);
    float a = rs[bg] * gsc[c];
    sa[t] = a;
    sb[t] = gbi[c] - mu[bg]*a;
  }
  __syncthreads();
  #pragma unroll
  for (int j = 0; j < 4; ++j){
    int id = t + j*256;
    int r = id >> 4, cq = id & 15;
    float4 v = *(const float4*)(x + ((size_t)b*Cc + c0 + r)*Nn + n0 + cq*4);
    float a = sa[r], bb = sb[r];
    yt[r*65 + cq*4 + 0] = v.x*a + bb;
    yt[r*65 + cq*4 + 1] = v.y*a + bb;
    yt[r*65 + cq*4 + 2] = v.z*a + bb;
    yt[r*65 + cq*4 + 3] = v.w*a + bb;
  }
  __syncthreads();
  int nl = t >> 2, cg = (t & 3) * 16;
  size_t base = ((size_t)b*Nn + n0 + nl)*Cc + c0 + cg;
  #pragma unroll
  for (int half = 0; half < 2; ++half){
    union { u16 u[8]; uint4 v; } Ph, Pl;
    #pragma unroll
    for (int u = 0; u < 8; ++u){
      float y = yt[(cg + half*8 + u)*65 + nl];
      u16 h = f2bf(y);
      Ph.u[u] = h; Pl.u[u] = f2bf(y - bf2f(h));
    }
    *(uint4*)(hhi + base + half*8) = Ph.v;
    *(uint4*)(hlo + base + half*8) = Pl.v;
  }
}

// ------------- Fused QKV conv GEMM (bf16 hi/lo, ~fp32 accurate) -------------
__global__ __launch_bounds__(256) void k_convqkv(const u16* __restrict__ WH, const u16* __restrict__ WL,
                                                 const u16* __restrict__ Hhi, const u16* __restrict__ Hlo,
                                                 const float* __restrict__ bq, const float* __restrict__ bk,
                                                 const float* __restrict__ bv,
                                                 const float* __restrict__ dq, const float* __restrict__ zq,
                                                 const float* __restrict__ dk, const float* __restrict__ zk,
                                                 const float* __restrict__ dv, const float* __restrict__ zv,
                                                 u8* __restrict__ qT8, u8* __restrict__ kT8,
                                                 u8* __restrict__ v8){
  int nt = blockIdx.x, ot = blockIdx.y, b = blockIdx.z;
  __shared__ u16 Lh[64*256], Ll[64*256];
  int t = threadIdx.x, lane = t & 63, wave = t >> 6;
  int lo16 = lane & 15, quad = lane >> 4;
  int o0 = ot*64 + wave*16;

  {
    const u16* hb = Hhi + ((size_t)b*Nn + nt*64) * 256;
    const u16* lb = Hlo + ((size_t)b*Nn + nt*64) * 256;
    #pragma unroll
    for (int j = 0; j < 8; ++j){
      int id = t + j*256;
      int r = id >> 5, ch = id & 31;
      int sw = (ch ^ (r & 15)) * 8;
      *(uint4*)(Lh + r*256 + sw) = *(const uint4*)(hb + (size_t)r*256 + ch*8);
      *(uint4*)(Ll + r*256 + sw) = *(const uint4*)(lb + (size_t)r*256 + ch*8);
    }
  }
  __syncthreads();

  const float* Bs[3] = {bq, bk, bv};
  const float* Dsr[3] = {dq, dk, dv};
  const float* Zs[3] = {zq, zk, zv};

  #pragma unroll
  for (int ws = 0; ws < 3; ++ws){
    bf16x8 awh[8], awl[8];
    {
      const u16* wbh = WH + (size_t)ws*65536 + (size_t)(o0 + lo16) * 256 + quad*8;
      const u16* wbl = WL + (size_t)ws*65536 + (size_t)(o0 + lo16) * 256 + quad*8;
      #pragma unroll
      for (int k = 0; k < 8; ++k){
        awh[k] = *(const bf16x8*)(wbh + k*32);
        awl[k] = *(const bf16x8*)(wbl + k*32);
      }
    }
    f32x4 zf = {0.f,0.f,0.f,0.f};
    f32x4 acc[4] = {zf, zf, zf, zf};
    #pragma unroll
    for (int k = 0; k < 8; ++k){
      #pragma unroll
      for (int ns = 0; ns < 4; ++ns){
        int r = ns*16 + lo16;
        int ph = ((k*4 + quad) ^ (r & 15)) * 8;
        bf16x8 bh = *(const bf16x8*)(Lh + r*256 + ph);
        bf16x8 bl = *(const bf16x8*)(Ll + r*256 + ph);
        acc[ns] = MFMA16(awh[k], bh, acc[ns]);
        acc[ns] = MFMA16(awl[k], bh, acc[ns]);
        acc[ns] = MFMA16(awh[k], bl, acc[ns]);
      }
    }
    float bia[4];
    #pragma unroll
    for (int r = 0; r < 4; ++r) bia[r] = Bs[ws][o0 + quad*4 + r];
    float z = Zs[ws][0]; float invd = 1.0f / Dsr[ws][0];

    if (ws < 2){
      u8* outT = (ws == 0) ? qT8 : kT8;
      #pragma unroll
      for (int ns = 0; ns < 4; ++ns){
        int n = nt*64 + ns*16 + lo16;
        u32 w = 0;
        #pragma unroll
        for (int r = 0; r < 4; ++r){
          float v = acc[ns][r] + bia[r];
          float xq = fminf(fmaxf(rintf(v*invd) + z, 0.f), 255.f);
          int qi = (int)rintf(xq - z);
          w |= ((u32)(qi & 255)) << (8*r);
        }
        *(u32*)(outT + ((size_t)b*Nn + n)*Cc + o0 + quad*4) = w;
      }
    } else {
      #pragma unroll
      for (int ns = 0; ns < 4; ++ns){
        int n = nt*64 + ns*16 + lo16;
        #pragma unroll
        for (int r = 0; r < 4; ++r){
          float v = acc[ns][r] + bia[r];
          float xq = fminf(fmaxf(rintf(v*invd) + z, 0.f), 255.f);
          int qi = (int)rintf(xq - z);
          v8[((size_t)b*Cc + o0 + quad*4 + r)*Nn + n] = (u8)(qi & 255);
        }
      }
    }
  }
}

// ------------- proj conv + residual -> f32 out -------------
__global__ __launch_bounds__(256) void k_conv(const u16* __restrict__ WH, const u16* __restrict__ WL,
                                              const u16* __restrict__ Hh,
                                              const float* __restrict__ bias,
                                              const float* __restrict__ xres, float* __restrict__ outF){
  int nt = blockIdx.x, ot = blockIdx.y, b = blockIdx.z;
  __shared__ u16 Lh[64*128];
  int t = threadIdx.x, lane = t & 63, wave = t >> 6;
  int lo16 = lane & 15, quad = lane >> 4;
  int o0 = ot*64 + wave*16;

  bf16x8 awh[8], awl[8];
  {
    const u16* wbh = WH + (size_t)3*65536 + (size_t)(o0 + lo16) * 256 + quad*8;
    const u16* wbl = WL + (size_t)3*65536 + (size_t)(o0 + lo16) * 256 + quad*8;
    #pragma unroll
    for (int k = 0; k < 8; ++k){
      awh[k] = *(const bf16x8*)(wbh + k*32);
      awl[k] = *(const bf16x8*)(wbl + k*32);
    }
  }
  f32x4 zf = {0.f,0.f,0.f,0.f};
  f32x4 acc[4] = {zf, zf, zf, zf};

  const u16* hb = Hh + ((size_t)b*Nn + nt*64) * 256;
  for (int kc = 0; kc < 2; ++kc){
    __syncthreads();
    for (int id = t; id < 64*16; id += 256){
      int r = id >> 4, ch = id & 15;
      int sw = (ch ^ (r & 7)) * 8;
      *(uint4*)(Lh + r*128 + sw) = *(const uint4*)(hb + (size_t)r*256 + kc*128 + ch*8);
    }
    __syncthreads();
    #pragma unroll
    for (int k4 = 0; k4 < 4; ++k4){
      int k = kc*4 + k4;
      #pragma unroll
      for (int ns = 0; ns < 4; ++ns){
        int r = ns*16 + lo16;
        int ch = ((k4*4 + quad) ^ (r & 7)) * 8;
        bf16x8 bh = *(const bf16x8*)(Lh + r*128 + ch);
        acc[ns] = MFMA16(awh[k], bh, acc[ns]);
        acc[ns] = MFMA16(awl[k], bh, acc[ns]);
      }
    }
  }

  float bia[4];
  #pragma unroll
  for (int r = 0; r < 4; ++r) bia[r] = bias[o0 + quad*4 + r];
  #pragma unroll
  for (int ns = 0; ns < 4; ++ns){
    int n = nt*64 + ns*16 + lo16;
    #pragma unroll
    for (int r = 0; r < 4; ++r){
      size_t a = ((size_t)b*Cc + o0 + quad*4 + r)*Nn + n;
      outF[a] = xres[a] + acc[ns][r] + bia[r];
    }
  }
}

static __device__ __forceinline__ void stage64x256(u8* dst, const u8* __restrict__ src, int t){
  #pragma unroll
  for (int j = 0; j < 4; ++j){
    int id = t + j*256; int r = id >> 4, ch = id & 15;
    *(uint4*)(dst + r*256 + ((ch ^ (r & 15)) << 4)) = *(const uint4*)(src + r*256 + ch*16);
  }
}

// ------------- merged: row norm^2 max + vsum -------------
static __device__ __forceinline__ int sq4(u32 w){
  int s = 0;
  #pragma unroll
  for (int j = 0; j < 4; ++j){ int v = (int)((signed char)((w >> (8*j)) & 0xffu)); s += v*v; }
  return s;
}
static __device__ __forceinline__ int ssum4(u32 w){
  return ((int)(w << 24) >> 24) + ((int)(w << 16) >> 24) + ((int)(w << 8) >> 24) + ((int)w >> 24);
}
__global__ __launch_bounds__(256) void k_normvs(const u8* __restrict__ qT8, const u8* __restrict__ kT8,
                                                const u8* __restrict__ v8,
                                                u32* __restrict__ stat, int* __restrict__ vsum){
  if (blockIdx.x < 128){
    int gid = blockIdx.x*256 + threadIdx.x;
    int which = gid >> 14;
    int rid = gid & 16383;
    const u8* row = (which ? kT8 : qT8) + (size_t)rid * 256;
    u32 acc = 0;
    const uint4* p = (const uint4*)row;
    #pragma unroll
    for (int i = 0; i < 16; ++i){
      uint4 w = p[i];
      acc += (u32)(sq4(w.x) + sq4(w.y) + sq4(w.z) + sq4(w.w));
    }
    #pragma unroll
    for (int msk = 32; msk > 0; msk >>= 1){
      u32 o = (u32)__shfl_xor((int)acc, msk, 64);
      acc = acc > o ? acc : o;
    }
    if ((threadIdx.x & 63) == 0)
      atomicMax(&stat[which*4 + (rid >> 12)], acc);
  } else {
    int row = blockIdx.x - 128;
    uint4 w = *(const uint4*)(v8 + (size_t)row*Nn + threadIdx.x*16);
    int s = ssum4(w.x) + ssum4(w.y) + ssum4(w.z) + ssum4(w.w);
    #pragma unroll
    for (int msk = 1; msk < 64; msk <<= 1) s += __shfl_xor(s, msk, 64);
    __shared__ int r4[4];
    if ((threadIdx.x & 63) == 0) r4[threadIdx.x >> 6] = s;
    __syncthreads();
    if (threadIdx.x == 0) vsum[row] = r4[0] + r4[1] + r4[2] + r4[3];
  }
}

// ------------- sum-exp pass -------------
__global__ __launch_bounds__(256) void k_sumexp(const u8* __restrict__ qT8, const u8* __restrict__ kT8,
                                                const u32* __restrict__ stat,
                                                const float* __restrict__ pdq, const float* __restrict__ pdk,
                                                float* __restrict__ Lp){
  int nt = blockIdx.x, mc = blockIdx.y, b = blockIdx.z;
  __shared__ u8 Kt[64*256];
  int t = threadIdx.x, lane = t & 63, wave = t >> 6;
  int lo16 = lane & 15, quad = lane >> 4;

  i32x4 a[4];
  {
    const u8* qb = qT8 + ((size_t)b*Nn + nt*64)*256;
    int ar = wave*16 + lo16;
    #pragma unroll
    for (int k = 0; k < 4; ++k)
      a[k] = *(const i32x4*)(qb + ar*256 + (k*4 + quad)*16);
  }
  float sc2 = pdq[0]*pdk[0]*0.0625f*LOG2E;
  float M2 = sc2 * sqrtf((float)stat[b] * (float)stat[4+b]);
  float lr[4] = {0.f,0.f,0.f,0.f};

  const u8* kbase = kT8 + ((size_t)b*Nn + mc*512)*256;
  for (int mt = 0; mt < 8; ++mt){
    __syncthreads();
    stage64x256(Kt, kbase + (size_t)mt*64*256, t);
    __syncthreads();
    #pragma unroll
    for (int ms = 0; ms < 4; ++ms){
      i32x4 acc = {0,0,0,0};
      int br = ms*16 + lo16;
      #pragma unroll
      for (int k = 0; k < 4; ++k){
        i32x4 bk_ = *(const i32x4*)(Kt + br*256 + (((k*4 + quad) ^ (br & 15)) << 4));
        acc = MFMA_I8(a[k], bk_, acc);
      }
      #pragma unroll
      for (int r = 0; r < 4; ++r)
        lr[r] += exp2f(fmaf((float)acc[r], sc2, -M2));
    }
  }
  #pragma unroll
  for (int msk = 1; msk < 16; msk <<= 1){
    #pragma unroll
    for (int r = 0; r < 4; ++r) lr[r] += __shfl_xor(lr[r], msk, 64);
  }
  if (lo16 == 0){
    #pragma unroll
    for (int r = 0; r < 4; ++r)
      Lp[((size_t)(b*8 + mc))*Nn + nt*64 + wave*16 + quad*4 + r] = lr[r];
  }
}

// ------------- fused quant+PV: per (nt,b) block (512 thr), loop all m:
// waves 0-3: S = K·Q^T (i8 MFMA), quantize with known invL, write P to a
// 4 KB LDS tile in B-frag-ready layout; all 8 waves: PV i8 MFMA. -------------
__global__ __launch_bounds__(512) void k_qpv(const u8* __restrict__ qT8, const u8* __restrict__ kT8,
                                             const u8* __restrict__ v8,
                                             const u32* __restrict__ stat,
                                             const float* __restrict__ pdq, const float* __restrict__ pdk,
                                             const float* __restrict__ pdw, const float* __restrict__ pzw,
                                             const float* __restrict__ Lp, const int* __restrict__ vsum,
                                             const float* __restrict__ pdv,
                                             u16* __restrict__ h2){
  int nt = blockIdx.x, b = blockIdx.y;
  __shared__ u8  Kt[64*256];   // K tile: [m][c], 16B-col xor swizzle
  __shared__ u8  Vt[256*64];   // V tile: [c][m], 16B-col xor swizzle
  __shared__ u32 Pt[64*16];    // P tile: [n][4 m-chunks x 4 dw], swizzled
  int t = threadIdx.x, lane = t & 63, w = t >> 6;
  int lo16 = lane & 15, q = lane >> 4;

  i32x4 zi = {0,0,0,0};
  i32x4 acc[2][4] = {{zi,zi,zi,zi},{zi,zi,zi,zi}};

  // QK setup (waves 0..3): B-frags = q rows for n-strip w*16..w*16+15
  i32x4 qf[4];
  float sc2 = pdq[0]*pdk[0]*0.0625f*LOG2E;
  float M2 = sc2 * sqrtf((float)stat[b] * (float)stat[4+b]);
  float crn = 0.f;
  float zw = pzw[0];
  if (w < 4){
    int n = nt*64 + w*16 + lo16;
    const u8* qb = qT8 + ((size_t)b*Nn + n)*256;
    #pragma unroll
    for (int kk = 0; kk < 4; ++kk)
      qf[kk] = *(const i32x4*)(qb + kk*64 + q*16);
    float Ls = 0.f;
    #pragma unroll
    for (int mc = 0; mc < 8; ++mc) Ls += Lp[((size_t)(b*8 + mc))*Nn + n];
    crn = __log2f(1.0f / (pdw[0] * Ls)) - M2;
  }

  // staging: K 2x uint4/thread, V 2x uint4/thread
  int krow0 = t >> 4, krow1 = 32 + (t >> 4), kch = t & 15;
  int vc0 = t >> 2,  vc1 = 128 + (t >> 2),  vch = t & 3;
  const u8* kb = kT8 + ((size_t)b*Nn)*256;
  const u8* vb = v8 + ((size_t)b*Cc)*Nn;
  int kdst0 = krow0*256 + ((kch ^ (krow0 & 15)) << 4);
  int kdst1 = krow1*256 + ((kch ^ (krow1 & 15)) << 4);
  int vdst0 = vc0*64 + ((vch ^ ((vc0 >> 1) & 3)) << 4);
  int vdst1 = vc1*64 + ((vch ^ ((vc1 >> 1) & 3)) << 4);

  uint4 kr0 = *(const uint4*)(kb + (size_t)krow0*256 + kch*16);
  uint4 kr1 = *(const uint4*)(kb + (size_t)krow1*256 + kch*16);
  uint4 vr0 = *(const uint4*)(vb + (size_t)vc0*Nn + vch*16);
  uint4 vr1 = *(const uint4*)(vb + (size_t)vc1*Nn + vch*16);

  for (int mt = 0; mt < 64; ++mt){
    if (mt) __syncthreads();                  // PV(mt-1) done before overwrite
    *(uint4*)(Kt + kdst0) = kr0;
    *(uint4*)(Kt + kdst1) = kr1;
    *(uint4*)(Vt + vdst0) = vr0;
    *(uint4*)(Vt + vdst1) = vr1;
    __syncthreads();                          // staging done
    if (mt < 63){
      int m1 = (mt + 1) * 64;
      kr0 = *(const uint4*)(kb + (size_t)(m1 + krow0)*256 + kch*16);
      kr1 = *(const uint4*)(kb + (size_t)(m1 + krow1)*256 + kch*16);
      vr0 = *(const uint4*)(vb + (size_t)vc0*Nn + m1 + vch*16);
      vr1 = *(const uint4*)(vb + (size_t)vc1*Nn + m1 + vch*16);
    }
    if (w < 4){
      int nrow = w*16 + lo16;
      #pragma unroll
      for (int ms = 0; ms < 4; ++ms){
        i32x4 s = {0,0,0,0};
        int mrow = ms*16 + lo16;
        #pragma unroll
        for (int kk = 0; kk < 4; ++kk){
          i32x4 af = *(const i32x4*)(Kt + mrow*256 + (((kk*4 + q) ^ (mrow & 15)) << 4));
          s = MFMA_I8(af, qf[kk], s);
        }
        u32 wp = 0;
        #pragma unroll
        for (int r = 0; r < 4; ++r){
          float at = exp2f(fmaf((float)s[r], sc2, crn));
          float y = fminf(fmaxf(rintf(at) + zw, 0.f), 255.f);
          wp = __builtin_amdgcn_cvt_pk_u8_f32(y, (u32)r, wp);
        }
        Pt[nrow*16 + ((ms ^ (nrow & 3) ^ ((nrow >> 2) & 3)) << 2) + q] = wp ^ 0x80808080u;
      }
    }
    __syncthreads();                          // P ready
    #pragma unroll
    for (int ct = 0; ct < 2; ++ct){
      int cr = w*32 + ct*16 + lo16;
      i32x4 af = *(const i32x4*)(Vt + cr*64 + ((q ^ ((cr >> 1) & 3)) << 4));
      #pragma unroll
      for (int ns = 0; ns < 4; ++ns){
        int pr = ns*16 + lo16;
        i32x4 bf_ = *(const i32x4*)(Pt + pr*16 + ((q ^ (pr & 3) ^ ((pr >> 2) & 3)) << 2));
        acc[ct][ns] = MFMA_I8(af, bf_, acc[ct][ns]);
      }
    }
  }

  float s = pdv[0] * pdw[0];
  float corr = s * (128.0f - zw);
  #pragma unroll
  for (int ct = 0; ct < 2; ++ct){
    int c0 = w*32 + ct*16 + q*4;
    float cv[4];
    #pragma unroll
    for (int r = 0; r < 4; ++r) cv[r] = corr * (float)vsum[b*Cc + c0 + r];
    #pragma unroll
    for (int ns = 0; ns < 4; ++ns){
      int n = nt*64 + ns*16 + lo16;
      U64c Uh;
      #pragma unroll
      for (int r = 0; r < 4; ++r)
        Uh.u[r] = f2bf(s*(float)acc[ct][ns][r] + cv[r]);
      *(uint2*)(h2 + ((size_t)b*Nn + n)*Cc + c0) = Uh.v;
    }
  }
}

extern "C" void kernel_launch(void* const* d_in, const int* in_sizes, int n_in,
                              void* d_out, int out_size, void* d_ws, size_t ws_size,
                              hipStream_t stream){
  (void)in_sizes; (void)n_in; (void)out_size; (void)ws_size;
  const float* x   = (const float*)d_in[0];
  const float* gsc = (const float*)d_in[1];
  const float* gbi = (const float*)d_in[2];
  const float* wq  = (const float*)d_in[3];
  const float* bq  = (const float*)d_in[4];
  const float* wk  = (const float*)d_in[5];
  const float* bk  = (const float*)d_in[6];
  const float* wv  = (const float*)d_in[7];
  const float* bv  = (const float*)d_in[8];
  const float* wp  = (const float*)d_in[9];
  const float* bp  = (const float*)d_in[10];
  const float* dq  = (const float*)d_in[11];
  const float* zq  = (const float*)d_in[12];
  const float* dk  = (const float*)d_in[13];
  const float* zk  = (const float*)d_in[14];
  const float* dv  = (const float*)d_in[15];
  const float* zv  = (const float*)d_in[16];
  const float* dw  = (const float*)d_in[17];
  const float* zw  = (const float*)d_in[18];
  float* out = (float*)d_out;

  const size_t SZT = (size_t)Bb*Nn*Cc;
  u16* hT_hi = (u16*)d_ws;
  u16* hT_lo = hT_hi + SZT;
  u16* h2    = hT_lo + SZT;
  u8*  qT8   = (u8*)(h2 + SZT);
  u8*  kT8   = qT8 + SZT;
  u8*  v8    = kT8 + SZT;
  u16* WH    = (u16*)(v8 + SZT);
  u16* WL    = WH + 4*65536;
  float* mu  = (float*)(WL + 4*65536);
  float* rs  = mu + 128;
  u32*  stat = (u32*)(rs + 128);
  int*  vsum = (int*)(stat + 8);
  float* Lp  = (float*)(vsum + Bb*Cc);

  k_gn_stats<<<dim3(Bb*NGRP), 256, 0, stream>>>(x, mu, rs);
  k_wsplit<<<dim3(1024), 256, 0, stream>>>(wq, wk, wv, wp, WH, WL);
  k_gn_apply<<<dim3(Nn/64, Cc/64, Bb), 256, 0, stream>>>(x, gsc, gbi, mu, rs, hT_hi, hT_lo);

  k_convqkv<<<dim3(Nn/64, 4, Bb), 256, 0, stream>>>(WH, WL, hT_hi, hT_lo,
                                                    bq, bk, bv, dq, zq, dk, zk, dv, zv,
                                                    qT8, kT8, v8);

  hipMemsetAsync(stat, 0, 8*sizeof(u32), stream);
  k_normvs<<<dim3(128 + Bb*Cc), 256, 0, stream>>>(qT8, kT8, v8, stat, vsum);
  k_sumexp<<<dim3(Nn/64, 8, Bb), 256, 0, stream>>>(qT8, kT8, stat, dq, dk, Lp);

  k_qpv<<<dim3(Nn/64, Bb), 512, 0, stream>>>(qT8, kT8, v8, stat, dq, dk, dw, zw, Lp, vsum, dv, h2);

  k_conv<<<dim3(Nn/64, 4, Bb), 256, 0, stream>>>(WH, WL, h2, bp, x, out);
}

// Round 9
// 278.011 us; speedup vs baseline: 1.0614x; 1.0614x over previous
//
#include <hip/hip_runtime.h>

// QuantAttnBlock on gfx950, round 9: attention = ONE kernel (k_qpv, 1024 thr,
// 16 waves). Pass1: balanced QK -> L (sum-exp, Cauchy-Schwarz shift). Pass2:
// balanced QK -> quantize -> P in LDS (B-frag layout) -> balanced PV.
// k_sumexp and Lp eliminated; every phase uses all 16 waves.

#define Bb 4
#define Cc 256
#define Nn 4096
#define NGRP 32
#define LOG2E 1.4426950408889634f

typedef unsigned short u16;
typedef unsigned int   u32;
typedef unsigned char  u8;
typedef __attribute__((ext_vector_type(8))) short bf16x8;
typedef __attribute__((ext_vector_type(4))) float f32x4;
typedef __attribute__((ext_vector_type(4))) int   i32x4;

#define MFMA16(a,b,c)    __builtin_amdgcn_mfma_f32_16x16x32_bf16((a),(b),(c),0,0,0)
#define MFMA_I8(a,b,c)   __builtin_amdgcn_mfma_i32_16x16x64_i8((a),(b),(c),0,0,0)

static __device__ __forceinline__ u16 f2bf(float x){
  u32 u = __float_as_uint(x);
  u += 0x7fffu + ((u >> 16) & 1u);
  return (u16)(u >> 16);
}
static __device__ __forceinline__ float bf2f(u16 h){ return __uint_as_float(((u32)h) << 16); }

union U64c { u16 u[4]; uint2 v; };

// ---------------- GroupNorm stats ----------------
__global__ __launch_bounds__(256) void k_gn_stats(const float* __restrict__ x,
                                                  float* __restrict__ mu, float* __restrict__ rs){
  int bg = blockIdx.x;
  const float4* p = (const float4*)(x + (size_t)bg * (8 * Nn));
  float s = 0.f, q = 0.f;
  for (int i = threadIdx.x; i < 8*Nn/4; i += 256){
    float4 v = p[i];
    s += v.x + v.y + v.z + v.w;
    q += v.x*v.x + v.y*v.y + v.z*v.z + v.w*v.w;
  }
  __shared__ float rsum[256], rsq[256];
  rsum[threadIdx.x] = s; rsq[threadIdx.x] = q;
  __syncthreads();
  for (int off = 128; off > 0; off >>= 1){
    if (threadIdx.x < off){ rsum[threadIdx.x] += rsum[threadIdx.x+off]; rsq[threadIdx.x] += rsq[threadIdx.x+off]; }
    __syncthreads();
  }
  if (threadIdx.x == 0){
    const float inv = 1.0f / (8*Nn);
    float m = rsum[0]*inv;
    float var = rsq[0]*inv - m*m;
    mu[bg] = m; rs[bg] = rsqrtf(var + 1e-6f);
  }
}

// ------------- weight split: 4 matrices f32 -> hi/lo bf16 -------------
__global__ __launch_bounds__(256) void k_wsplit(const float* __restrict__ wq, const float* __restrict__ wk,
                                                const float* __restrict__ wv, const float* __restrict__ wp,
                                                u16* __restrict__ WH, u16* __restrict__ WL){
  int gid = blockIdx.x*256 + threadIdx.x;
  int mat = gid >> 16, idx = gid & 65535;
  const float* src = (mat == 0) ? wq : (mat == 1) ? wk : (mat == 2) ? wv : wp;
  float w = src[idx];
  u16 h = f2bf(w);
  WH[gid] = h;
  WL[gid] = f2bf(w - bf2f(h));
}

// ------------- GroupNorm apply + transpose -> hT hi/lo [b][n][c] -------------
__global__ __launch_bounds__(256) void k_gn_apply(const float* __restrict__ x,
                                                  const float* __restrict__ gsc, const float* __restrict__ gbi,
                                                  const float* __restrict__ mu, const float* __restrict__ rs,
                                                  u16* __restrict__ hhi, u16* __restrict__ hlo){
  int nt = blockIdx.x, ct = blockIdx.y, b = blockIdx.z;
  int n0 = nt*64, c0 = ct*64;
  __shared__ float yt[64*65];
  __shared__ float sa[64], sb[64];
  int t = threadIdx.x;
  if (t < 64){
    int c = c0 + t;
    int bg = b*NGRP + (c >> 3);
    float a = rs[bg] * gsc[c];
    sa[t] = a;
    sb[t] = gbi[c] - mu[bg]*a;
  }
  __syncthreads();
  #pragma unroll
  for (int j = 0; j < 4; ++j){
    int id = t + j*256;
    int r = id >> 4, cq = id & 15;
    float4 v = *(const float4*)(x + ((size_t)b*Cc + c0 + r)*Nn + n0 + cq*4);
    float a = sa[r], bb = sb[r];
    yt[r*65 + cq*4 + 0] = v.x*a + bb;
    yt[r*65 + cq*4 + 1] = v.y*a + bb;
    yt[r*65 + cq*4 + 2] = v.z*a + bb;
    yt[r*65 + cq*4 + 3] = v.w*a + bb;
  }
  __syncthreads();
  int nl = t >> 2, cg = (t & 3) * 16;
  size_t base = ((size_t)b*Nn + n0 + nl)*Cc + c0 + cg;
  #pragma unroll
  for (int half = 0; half < 2; ++half){
    union { u16 u[8]; uint4 v; } Ph, Pl;
    #pragma unroll
    for (int u = 0; u < 8; ++u){
      float y = yt[(cg + half*8 + u)*65 + nl];
      u16 h = f2bf(y);
      Ph.u[u] = h; Pl.u[u] = f2bf(y - bf2f(h));
    }
    *(uint4*)(hhi + base + half*8) = Ph.v;
    *(uint4*)(hlo + base + half*8) = Pl.v;
  }
}

// ------------- Fused QKV conv GEMM (bf16 hi/lo, ~fp32 accurate) -------------
__global__ __launch_bounds__(256) void k_convqkv(const u16* __restrict__ WH, const u16* __restrict__ WL,
                                                 const u16* __restrict__ Hhi, const u16* __restrict__ Hlo,
                                                 const float* __restrict__ bq, const float* __restrict__ bk,
                                                 const float* __restrict__ bv,
                                                 const float* __restrict__ dq, const float* __restrict__ zq,
                                                 const float* __restrict__ dk, const float* __restrict__ zk,
                                                 const float* __restrict__ dv, const float* __restrict__ zv,
                                                 u8* __restrict__ qT8, u8* __restrict__ kT8,
                                                 u8* __restrict__ v8){
  int nt = blockIdx.x, ot = blockIdx.y, b = blockIdx.z;
  __shared__ u16 Lh[64*256], Ll[64*256];
  int t = threadIdx.x, lane = t & 63, wave = t >> 6;
  int lo16 = lane & 15, quad = lane >> 4;
  int o0 = ot*64 + wave*16;

  {
    const u16* hb = Hhi + ((size_t)b*Nn + nt*64) * 256;
    const u16* lb = Hlo + ((size_t)b*Nn + nt*64) * 256;
    #pragma unroll
    for (int j = 0; j < 8; ++j){
      int id = t + j*256;
      int r = id >> 5, ch = id & 31;
      int sw = (ch ^ (r & 15)) * 8;
      *(uint4*)(Lh + r*256 + sw) = *(const uint4*)(hb + (size_t)r*256 + ch*8);
      *(uint4*)(Ll + r*256 + sw) = *(const uint4*)(lb + (size_t)r*256 + ch*8);
    }
  }
  __syncthreads();

  const float* Bs[3] = {bq, bk, bv};
  const float* Dsr[3] = {dq, dk, dv};
  const float* Zs[3] = {zq, zk, zv};

  #pragma unroll
  for (int ws = 0; ws < 3; ++ws){
    bf16x8 awh[8], awl[8];
    {
      const u16* wbh = WH + (size_t)ws*65536 + (size_t)(o0 + lo16) * 256 + quad*8;
      const u16* wbl = WL + (size_t)ws*65536 + (size_t)(o0 + lo16) * 256 + quad*8;
      #pragma unroll
      for (int k = 0; k < 8; ++k){
        awh[k] = *(const bf16x8*)(wbh + k*32);
        awl[k] = *(const bf16x8*)(wbl + k*32);
      }
    }
    f32x4 zf = {0.f,0.f,0.f,0.f};
    f32x4 acc[4] = {zf, zf, zf, zf};
    #pragma unroll
    for (int k = 0; k < 8; ++k){
      #pragma unroll
      for (int ns = 0; ns < 4; ++ns){
        int r = ns*16 + lo16;
        int ph = ((k*4 + quad) ^ (r & 15)) * 8;
        bf16x8 bh = *(const bf16x8*)(Lh + r*256 + ph);
        bf16x8 bl = *(const bf16x8*)(Ll + r*256 + ph);
        acc[ns] = MFMA16(awh[k], bh, acc[ns]);
        acc[ns] = MFMA16(awl[k], bh, acc[ns]);
        acc[ns] = MFMA16(awh[k], bl, acc[ns]);
      }
    }
    float bia[4];
    #pragma unroll
    for (int r = 0; r < 4; ++r) bia[r] = Bs[ws][o0 + quad*4 + r];
    float z = Zs[ws][0]; float invd = 1.0f / Dsr[ws][0];

    if (ws < 2){
      u8* outT = (ws == 0) ? qT8 : kT8;
      #pragma unroll
      for (int ns = 0; ns < 4; ++ns){
        int n = nt*64 + ns*16 + lo16;
        u32 w = 0;
        #pragma unroll
        for (int r = 0; r < 4; ++r){
          float v = acc[ns][r] + bia[r];
          float xq = fminf(fmaxf(rintf(v*invd) + z, 0.f), 255.f);
          int qi = (int)rintf(xq - z);
          w |= ((u32)(qi & 255)) << (8*r);
        }
        *(u32*)(outT + ((size_t)b*Nn + n)*Cc + o0 + quad*4) = w;
      }
    } else {
      #pragma unroll
      for (int ns = 0; ns < 4; ++ns){
        int n = nt*64 + ns*16 + lo16;
        #pragma unroll
        for (int r = 0; r < 4; ++r){
          float v = acc[ns][r] + bia[r];
          float xq = fminf(fmaxf(rintf(v*invd) + z, 0.f), 255.f);
          int qi = (int)rintf(xq - z);
          v8[((size_t)b*Cc + o0 + quad*4 + r)*Nn + n] = (u8)(qi & 255);
        }
      }
    }
  }
}

// ------------- proj conv + residual -> f32 out -------------
__global__ __launch_bounds__(256) void k_conv(const u16* __restrict__ WH, const u16* __restrict__ WL,
                                              const u16* __restrict__ Hh,
                                              const float* __restrict__ bias,
                                              const float* __restrict__ xres, float* __restrict__ outF){
  int nt = blockIdx.x, ot = blockIdx.y, b = blockIdx.z;
  __shared__ u16 Lh[64*128];
  int t = threadIdx.x, lane = t & 63, wave = t >> 6;
  int lo16 = lane & 15, quad = lane >> 4;
  int o0 = ot*64 + wave*16;

  bf16x8 awh[8], awl[8];
  {
    const u16* wbh = WH + (size_t)3*65536 + (size_t)(o0 + lo16) * 256 + quad*8;
    const u16* wbl = WL + (size_t)3*65536 + (size_t)(o0 + lo16) * 256 + quad*8;
    #pragma unroll
    for (int k = 0; k < 8; ++k){
      awh[k] = *(const bf16x8*)(wbh + k*32);
      awl[k] = *(const bf16x8*)(wbl + k*32);
    }
  }
  f32x4 zf = {0.f,0.f,0.f,0.f};
  f32x4 acc[4] = {zf, zf, zf, zf};

  const u16* hb = Hh + ((size_t)b*Nn + nt*64) * 256;
  for (int kc = 0; kc < 2; ++kc){
    __syncthreads();
    for (int id = t; id < 64*16; id += 256){
      int r = id >> 4, ch = id & 15;
      int sw = (ch ^ (r & 7)) * 8;
      *(uint4*)(Lh + r*128 + sw) = *(const uint4*)(hb + (size_t)r*256 + kc*128 + ch*8);
    }
    __syncthreads();
    #pragma unroll
    for (int k4 = 0; k4 < 4; ++k4){
      int k = kc*4 + k4;
      #pragma unroll
      for (int ns = 0; ns < 4; ++ns){
        int r = ns*16 + lo16;
        int ch = ((k4*4 + quad) ^ (r & 7)) * 8;
        bf16x8 bh = *(const bf16x8*)(Lh + r*128 + ch);
        acc[ns] = MFMA16(awh[k], bh, acc[ns]);
        acc[ns] = MFMA16(awl[k], bh, acc[ns]);
      }
    }
  }

  float bia[4];
  #pragma unroll
  for (int r = 0; r < 4; ++r) bia[r] = bias[o0 + quad*4 + r];
  #pragma unroll
  for (int ns = 0; ns < 4; ++ns){
    int n = nt*64 + ns*16 + lo16;
    #pragma unroll
    for (int r = 0; r < 4; ++r){
      size_t a = ((size_t)b*Cc + o0 + quad*4 + r)*Nn + n;
      outF[a] = xres[a] + acc[ns][r] + bia[r];
    }
  }
}

// ------------- merged: row norm^2 max + vsum -------------
static __device__ __forceinline__ int sq4(u32 w){
  int s = 0;
  #pragma unroll
  for (int j = 0; j < 4; ++j){ int v = (int)((signed char)((w >> (8*j)) & 0xffu)); s += v*v; }
  return s;
}
static __device__ __forceinline__ int ssum4(u32 w){
  return ((int)(w << 24) >> 24) + ((int)(w << 16) >> 24) + ((int)(w << 8) >> 24) + ((int)w >> 24);
}
__global__ __launch_bounds__(256) void k_normvs(const u8* __restrict__ qT8, const u8* __restrict__ kT8,
                                                const u8* __restrict__ v8,
                                                u32* __restrict__ stat, int* __restrict__ vsum){
  if (blockIdx.x < 128){
    int gid = blockIdx.x*256 + threadIdx.x;
    int which = gid >> 14;
    int rid = gid & 16383;
    const u8* row = (which ? kT8 : qT8) + (size_t)rid * 256;
    u32 acc = 0;
    const uint4* p = (const uint4*)row;
    #pragma unroll
    for (int i = 0; i < 16; ++i){
      uint4 w = p[i];
      acc += (u32)(sq4(w.x) + sq4(w.y) + sq4(w.z) + sq4(w.w));
    }
    #pragma unroll
    for (int msk = 32; msk > 0; msk >>= 1){
      u32 o = (u32)__shfl_xor((int)acc, msk, 64);
      acc = acc > o ? acc : o;
    }
    if ((threadIdx.x & 63) == 0)
      atomicMax(&stat[which*4 + (rid >> 12)], acc);
  } else {
    int row = blockIdx.x - 128;
    uint4 w = *(const uint4*)(v8 + (size_t)row*Nn + threadIdx.x*16);
    int s = ssum4(w.x) + ssum4(w.y) + ssum4(w.z) + ssum4(w.w);
    #pragma unroll
    for (int msk = 1; msk < 64; msk <<= 1) s += __shfl_xor(s, msk, 64);
    __shared__ int r4[4];
    if ((threadIdx.x & 63) == 0) r4[threadIdx.x >> 6] = s;
    __syncthreads();
    if (threadIdx.x == 0) vsum[row] = r4[0] + r4[1] + r4[2] + r4[3];
  }
}

// ------------- fused attention: 1024 thr (16 waves), per (nt,b).
// Pass1: QK -> L. Pass2: QK -> quantize -> Pt (LDS, B-frag layout) -> PV.
// All 16 waves active in every phase. -------------
__global__ __launch_bounds__(1024) void k_qpv(const u8* __restrict__ qT8, const u8* __restrict__ kT8,
                                              const u8* __restrict__ v8,
                                              const u32* __restrict__ stat,
                                              const float* __restrict__ pdq, const float* __restrict__ pdk,
                                              const float* __restrict__ pdw, const float* __restrict__ pzw,
                                              const int* __restrict__ vsum,
                                              const float* __restrict__ pdv,
                                              u16* __restrict__ h2){
  int nt = blockIdx.x, b = blockIdx.y;
  __shared__ u8  Kt[64*256];     // K tile [m][c]
  __shared__ u8  Vt[256*64];     // V tile [c][m]
  __shared__ u32 Pt[64*16];      // P tile [n][16 dw], swizzled (B-frag ready)
  __shared__ float Lbuf[4][4][16];
  int t = threadIdx.x, lane = t & 63, w = t >> 6;
  int lo16 = lane & 15, q = lane >> 4;
  int ms = w & 3, nsq = w >> 2;

  float sc2 = pdq[0]*pdk[0]*0.0625f*LOG2E;
  float M2 = sc2 * sqrtf((float)stat[b] * (float)stat[4+b]);
  float zw = pzw[0];

  // Q B-fragments: rows n = nt*64 + nsq*16 + lo16
  i32x4 qf[4];
  {
    const u8* qb = qT8 + ((size_t)b*Nn + nt*64 + nsq*16 + lo16)*256;
    #pragma unroll
    for (int kk = 0; kk < 4; ++kk)
      qf[kk] = *(const i32x4*)(qb + kk*64 + q*16);
  }

  // staging indices (1024 thr: 1 uint4 each for Kt and Vt)
  int krow = t >> 4, kch = t & 15;
  int kdst = krow*256 + ((kch ^ (krow & 15)) << 4);
  const u8* kb = kT8 + (size_t)b*Nn*256;
  int vc = t >> 2, vch = t & 3;
  int vdst = vc*64 + ((vch ^ ((vc >> 1) & 3)) << 4);
  const u8* vrow = v8 + ((size_t)(b*Cc + vc))*Nn + vch*16;

  int mrow = ms*16 + lo16;
  int kofs[4];
  #pragma unroll
  for (int kk = 0; kk < 4; ++kk) kofs[kk] = mrow*256 + (((kk*4 + q) ^ (mrow & 15)) << 4);

  // ---- pass 1: L(n) ----
  float lr = 0.f;
  {
    uint4 kr = *(const uint4*)(kb + (size_t)krow*256 + kch*16);
    for (int mt = 0; mt < 64; ++mt){
      if (mt) __syncthreads();
      *(uint4*)(Kt + kdst) = kr;
      __syncthreads();
      if (mt < 63) kr = *(const uint4*)(kb + (size_t)((mt+1)*64 + krow)*256 + kch*16);
      i32x4 s = {0,0,0,0};
      #pragma unroll
      for (int kk = 0; kk < 4; ++kk)
        s = MFMA_I8(*(const i32x4*)(Kt + kofs[kk]), qf[kk], s);
      #pragma unroll
      for (int r = 0; r < 4; ++r)
        lr += exp2f(fmaf((float)s[r], sc2, -M2));
    }
  }
  lr += __shfl_xor(lr, 16, 64);
  lr += __shfl_xor(lr, 32, 64);
  if (lane < 16) Lbuf[nsq][ms][lo16] = lr;
  __syncthreads();
  float Ls = Lbuf[nsq][0][lo16] + Lbuf[nsq][1][lo16] + Lbuf[nsq][2][lo16] + Lbuf[nsq][3][lo16];
  float crn = __log2f(1.0f / (pdw[0] * Ls)) - M2;

  // ---- pass 2: QK -> quant -> Pt -> PV ----
  i32x4 zi = {0,0,0,0};
  i32x4 acc[4] = {zi,zi,zi,zi};
  int nrow = nsq*16 + lo16;
  int pdst = nrow*16 + ((ms ^ (nrow & 3) ^ ((nrow >> 2) & 3)) << 2) + q;
  int crv = w*16 + lo16;
  int vofs = crv*64 + ((q ^ ((crv >> 1) & 3)) << 4);
  int pofs[4];
  #pragma unroll
  for (int ns = 0; ns < 4; ++ns){
    int pr = ns*16 + lo16;
    pofs[ns] = pr*16 + ((q ^ (pr & 3) ^ ((pr >> 2) & 3)) << 2);
  }
  {
    uint4 kr = *(const uint4*)(kb + (size_t)krow*256 + kch*16);
    uint4 vr = *(const uint4*)(vrow);
    for (int mt = 0; mt < 64; ++mt){
      __syncthreads();                        // PV(mt-1)/Lbuf reads done
      *(uint4*)(Kt + kdst) = kr;
      *(uint4*)(Vt + vdst) = vr;
      __syncthreads();                        // staging done
      if (mt < 63){
        kr = *(const uint4*)(kb + (size_t)((mt+1)*64 + krow)*256 + kch*16);
        vr = *(const uint4*)(vrow + (mt+1)*64);
      }
      i32x4 s = {0,0,0,0};
      #pragma unroll
      for (int kk = 0; kk < 4; ++kk)
        s = MFMA_I8(*(const i32x4*)(Kt + kofs[kk]), qf[kk], s);
      u32 wp = 0;
      #pragma unroll
      for (int r = 0; r < 4; ++r){
        float at = exp2f(fmaf((float)s[r], sc2, crn));
        float y = fminf(fmaxf(rintf(at) + zw, 0.f), 255.f);
        wp = __builtin_amdgcn_cvt_pk_u8_f32(y, (u32)r, wp);
      }
      Pt[pdst] = wp ^ 0x80808080u;
      __syncthreads();                        // P ready
      i32x4 af = *(const i32x4*)(Vt + vofs);
      #pragma unroll
      for (int ns = 0; ns < 4; ++ns)
        acc[ns] = MFMA_I8(af, *(const i32x4*)(Pt + pofs[ns]), acc[ns]);
    }
  }

  float s = pdv[0] * pdw[0];
  float corr = s * (128.0f - zw);
  int c0 = w*16 + q*4;
  float cv[4];
  #pragma unroll
  for (int r = 0; r < 4; ++r) cv[r] = corr * (float)vsum[b*Cc + c0 + r];
  #pragma unroll
  for (int ns = 0; ns < 4; ++ns){
    int n = nt*64 + ns*16 + lo16;
    U64c Uh;
    #pragma unroll
    for (int r = 0; r < 4; ++r)
      Uh.u[r] = f2bf(s*(float)acc[ns][r] + cv[r]);
    *(uint2*)(h2 + ((size_t)b*Nn + n)*Cc + c0) = Uh.v;
  }
}

extern "C" void kernel_launch(void* const* d_in, const int* in_sizes, int n_in,
                              void* d_out, int out_size, void* d_ws, size_t ws_size,
                              hipStream_t stream){
  (void)in_sizes; (void)n_in; (void)out_size; (void)ws_size;
  const float* x   = (const float*)d_in[0];
  const float* gsc = (const float*)d_in[1];
  const float* gbi = (const float*)d_in[2];
  const float* wq  = (const float*)d_in[3];
  const float* bq  = (const float*)d_in[4];
  const float* wk  = (const float*)d_in[5];
  const float* bk  = (const float*)d_in[6];
  const float* wv  = (const float*)d_in[7];
  const float* bv  = (const float*)d_in[8];
  const float* wp  = (const float*)d_in[9];
  const float* bp  = (const float*)d_in[10];
  const float* dq  = (const float*)d_in[11];
  const float* zq  = (const float*)d_in[12];
  const float* dk  = (const float*)d_in[13];
  const float* zk  = (const float*)d_in[14];
  const float* dv  = (const float*)d_in[15];
  const float* zv  = (const float*)d_in[16];
  const float* dw  = (const float*)d_in[17];
  const float* zw  = (const float*)d_in[18];
  float* out = (float*)d_out;

  const size_t SZT = (size_t)Bb*Nn*Cc;
  u16* hT_hi = (u16*)d_ws;
  u16* hT_lo = hT_hi + SZT;
  u16* h2    = hT_lo + SZT;
  u8*  qT8   = (u8*)(h2 + SZT);
  u8*  kT8   = qT8 + SZT;
  u8*  v8    = kT8 + SZT;
  u16* WH    = (u16*)(v8 + SZT);
  u16* WL    = WH + 4*65536;
  float* mu  = (float*)(WL + 4*65536);
  float* rs  = mu + 128;
  u32*  stat = (u32*)(rs + 128);
  int*  vsum = (int*)(stat + 8);

  k_gn_stats<<<dim3(Bb*NGRP), 256, 0, stream>>>(x, mu, rs);
  k_wsplit<<<dim3(1024), 256, 0, stream>>>(wq, wk, wv, wp, WH, WL);
  k_gn_apply<<<dim3(Nn/64, Cc/64, Bb), 256, 0, stream>>>(x, gsc, gbi, mu, rs, hT_hi, hT_lo);

  k_convqkv<<<dim3(Nn/64, 4, Bb), 256, 0, stream>>>(WH, WL, hT_hi, hT_lo,
                                                    bq, bk, bv, dq, zq, dk, zk, dv, zv,
                                                    qT8, kT8, v8);

  hipMemsetAsync(stat, 0, 8*sizeof(u32), stream);
  k_normvs<<<dim3(128 + Bb*Cc), 256, 0, stream>>>(qT8, kT8, v8, stat, vsum);

  k_qpv<<<dim3(Nn/64, Bb), 1024, 0, stream>>>(qT8, kT8, v8, stat, dq, dk, dw, zw, vsum, dv, h2);

  k_conv<<<dim3(Nn/64, 4, Bb), 256, 0, stream>>>(WH, WL, h2, bp, x, out);
}